// Round 1
// baseline (4786.617 us; speedup 1.0000x reference)
//
#include <hip/hip_runtime.h>

// K-means assignment: out[n] = argmin_k ( Cnorm[k] - 2 * dot(x[n,:], C[:,k]) )
// x: [N=32768, D=1024] f32 (row-major), C: [D=1024, K=4096] f32 (row-major),
// Cnorm: [K] f32, out: [N] int32.
// |x|^2 omitted (constant per row, argmin-invariant).

constexpr int N_ROWS = 32768;
constexpr int D_DIM  = 1024;
constexpr int K_CENT = 4096;
constexpr int BM = 64;   // rows per block
constexpr int BN = 64;   // centroid columns per K-chunk
constexpr int BK = 32;   // D-depth per LDS stage

__global__ __launch_bounds__(256, 2) void kmeans_assign_f32(
    const float* __restrict__ x, const float* __restrict__ Cm,
    const float* __restrict__ Cnorm, int* __restrict__ out)
{
    __shared__ float xs[BK][BM];   // x tile, transposed: xs[kk][m]
    __shared__ float cs[BK][BN];   // C tile: cs[kk][n]

    const int tid = threadIdx.x;
    const int tx  = tid & 15;      // column-thread 0..15 (4 cols each)
    const int ty  = tid >> 4;      // row-thread    0..15 (4 rows each)
    const int row0 = blockIdx.x * BM;

    // x-tile loader mapping: 64 rows x 8 float4; thread covers rows xr, xr+32
    const int xr = tid >> 3;       // 0..31
    const int xc = tid & 7;        // 0..7  (float4 chunk)
    // C-tile loader mapping: 32 rows x 16 float4; thread covers rows cr, cr+16
    const int cr = tid >> 4;       // 0..15
    const int cc = tid & 15;       // 0..15 (float4 chunk)

    float best[4];
    int   bidx[4];
#pragma unroll
    for (int i = 0; i < 4; ++i) { best[i] = 3.4e38f; bidx[i] = 0; }

    for (int kc = 0; kc < K_CENT; kc += BN) {
        float acc[16];
#pragma unroll
        for (int i = 0; i < 16; ++i) acc[i] = 0.0f;

        for (int kd = 0; kd < D_DIM; kd += BK) {
            // issue global loads early (in flight across the barrier)
            const float4 xv0 = *(const float4*)&x[(size_t)(row0 + xr)      * D_DIM + kd + xc * 4];
            const float4 xv1 = *(const float4*)&x[(size_t)(row0 + xr + 32) * D_DIM + kd + xc * 4];
            const float4 cv0 = *(const float4*)&Cm[(size_t)(kd + cr)      * K_CENT + kc + cc * 4];
            const float4 cv1 = *(const float4*)&Cm[(size_t)(kd + cr + 16) * K_CENT + kc + cc * 4];

            __syncthreads();   // previous iteration's readers done
            xs[xc*4+0][xr]    = xv0.x; xs[xc*4+1][xr]    = xv0.y;
            xs[xc*4+2][xr]    = xv0.z; xs[xc*4+3][xr]    = xv0.w;
            xs[xc*4+0][xr+32] = xv1.x; xs[xc*4+1][xr+32] = xv1.y;
            xs[xc*4+2][xr+32] = xv1.z; xs[xc*4+3][xr+32] = xv1.w;
            *(float4*)&cs[cr][cc*4]      = cv0;
            *(float4*)&cs[cr+16][cc*4]   = cv1;
            __syncthreads();

#pragma unroll
            for (int kk = 0; kk < BK; ++kk) {
                const float4 a = *(const float4*)&xs[kk][ty*4];
                const float4 b = *(const float4*)&cs[kk][tx*4];
                acc[ 0] += a.x*b.x; acc[ 1] += a.x*b.y; acc[ 2] += a.x*b.z; acc[ 3] += a.x*b.w;
                acc[ 4] += a.y*b.x; acc[ 5] += a.y*b.y; acc[ 6] += a.y*b.z; acc[ 7] += a.y*b.w;
                acc[ 8] += a.z*b.x; acc[ 9] += a.z*b.y; acc[10] += a.z*b.z; acc[11] += a.z*b.w;
                acc[12] += a.w*b.x; acc[13] += a.w*b.y; acc[14] += a.w*b.z; acc[15] += a.w*b.w;
            }
        }

        // argmin epilogue for this K-chunk (k ascending; strict < keeps first index)
        const float4 cn = *(const float4*)&Cnorm[kc + tx*4];
        const float cnv[4] = {cn.x, cn.y, cn.z, cn.w};
#pragma unroll
        for (int i = 0; i < 4; ++i) {
#pragma unroll
            for (int j = 0; j < 4; ++j) {
                const float dist = cnv[j] - 2.0f * acc[i*4+j];
                const int   idx  = kc + tx*4 + j;
                if (dist < best[i]) { best[i] = dist; bidx[i] = idx; }
            }
        }
    }

    // reduce across the 16 column-threads (same ty, tx = lane&15): min, tie -> smaller idx
#pragma unroll
    for (int i = 0; i < 4; ++i) {
        float d  = best[i];
        int   ix = bidx[i];
#pragma unroll
        for (int off = 1; off < 16; off <<= 1) {
            const float od = __shfl_xor(d,  off, 64);
            const int   oi = __shfl_xor(ix, off, 64);
            if (od < d || (od == d && oi < ix)) { d = od; ix = oi; }
        }
        if (tx == 0) out[row0 + ty*4 + i] = ix;
    }
}

extern "C" void kernel_launch(void* const* d_in, const int* in_sizes, int n_in,
                              void* d_out, int out_size, void* d_ws, size_t ws_size,
                              hipStream_t stream) {
    const float* x     = (const float*)d_in[0];
    const float* Cm    = (const float*)d_in[1];
    const float* Cnorm = (const float*)d_in[2];
    int* out = (int*)d_out;

    dim3 grid(N_ROWS / BM);   // 512 blocks
    dim3 block(256);
    kmeans_assign_f32<<<grid, block, 0, stream>>>(x, Cm, Cnorm, out);
}

// Round 3
// 904.278 us; speedup vs baseline: 5.2933x; 5.2933x over previous
//
#include <hip/hip_runtime.h>
#include <cstdint>
#include <cstddef>

typedef _Float16 half8 __attribute__((ext_vector_type(8)));
typedef _Float16 half4 __attribute__((ext_vector_type(4)));
typedef float    floatx4 __attribute__((ext_vector_type(4)));

constexpr int N_ROWS = 32768;
constexpr int D_DIM  = 1024;
constexpr int K_CENT = 4096;

// ============================================================================
// Pre-pass: C[d][k] f32 -> C_hiT[k][d], C_loT[k][d] fp16 (transposed hi/lo split)
// ============================================================================
__global__ __launch_bounds__(256) void convert_C_kernel(
    const float* __restrict__ C, _Float16* __restrict__ ChiT, _Float16* __restrict__ CloT)
{
    __shared__ float tile[32][33];
    const int bk = blockIdx.x;          // k-tile 0..127
    const int bd = blockIdx.y;          // d-tile 0..31
    const int t  = threadIdx.x;
    const int r  = t >> 3;              // 0..31
    const int c4 = (t & 7) * 4;         // 0..28
    const float4 v = *(const float4*)&C[(size_t)(bd * 32 + r) * K_CENT + bk * 32 + c4];
    tile[r][c4 + 0] = v.x; tile[r][c4 + 1] = v.y;
    tile[r][c4 + 2] = v.z; tile[r][c4 + 3] = v.w;
    __syncthreads();
    half4 h, l;
#pragma unroll
    for (int i = 0; i < 4; ++i) {
        const float f  = tile[c4 + i][r];
        const _Float16 hi = (_Float16)f;
        h[i] = hi;
        l[i] = (_Float16)(f - (float)hi);
    }
    *(half4*)&ChiT[(size_t)(bk * 32 + r) * D_DIM + bd * 32 + c4] = h;
    *(half4*)&CloT[(size_t)(bk * 32 + r) * D_DIM + bd * 32 + c4] = l;
}

// ============================================================================
// Main kernel: 128x256 tile, 8 waves (each 64x64), BK=32, double-buffered LDS.
// dist = Cnorm[k] - 2 * dot(x[n], C[:,k]); dot via hi*hi + hi*lo + lo*hi fp16 MFMA.
// ============================================================================
constexpr int BM = 128, BN = 256, BK = 32;
constexpr int HBUF = 24576;            // halves per LDS buffer (48 KB)
constexpr int XH = 0;                  // x_hi  [8 msub][16 r][4 kg][8]
constexpr int XL = 4096;               // x_lo
constexpr int CHOFF = 8192;            // C_hi  [16 nsub][16 c][4 kg][8]
constexpr int CLOFF = 16384;           // C_lo

__device__ __forceinline__ void gload_lds16(const void* g, void* l) {
    __builtin_amdgcn_global_load_lds(
        (const __attribute__((address_space(1))) uint32_t*)g,
        (__attribute__((address_space(3))) uint32_t*)l, 16, 0, 0);
}

__device__ __forceinline__ void cvt4(const float4 v, half4& h, half4& l) {
    const _Float16 h0 = (_Float16)v.x, h1 = (_Float16)v.y;
    const _Float16 h2 = (_Float16)v.z, h3 = (_Float16)v.w;
    h = (half4){h0, h1, h2, h3};
    l = (half4){(_Float16)(v.x - (float)h0), (_Float16)(v.y - (float)h1),
                (_Float16)(v.z - (float)h2), (_Float16)(v.w - (float)h3)};
}

// write 4 converted x elements (row r, k-base kb within stage) into buffer
__device__ __forceinline__ void write_x(_Float16* buf, const float4 v, int r, int kb) {
    half4 h, l;
    cvt4(v, h, l);
    const int kg  = kb >> 3;
    const int hs  = (kb >> 2) & 1;
    const int kge = kg ^ ((r >> 1) & 3);                       // XOR swizzle
    const int base = (r >> 4) * 512 + (r & 15) * 32 + kge * 8 + hs * 4;
    *(half4*)(buf + XH + base) = h;
    *(half4*)(buf + XL + base) = l;
}

__global__ __launch_bounds__(512, 2) void kmeans_mfma_kernel(
    const float* __restrict__ x, const _Float16* __restrict__ ChiT,
    const _Float16* __restrict__ CloT, const float* __restrict__ Cnorm,
    int* __restrict__ out)
{
    __shared__ _Float16 lds[2][HBUF];
    __shared__ float red_d[2][64][4];   // cross-wave argmin scratch
    __shared__ int   red_i[2][64][4];

    const int tid  = threadIdx.x;
    const int lane = tid & 63;
    const int wid  = tid >> 6;          // 0..7
    const int wm   = wid >> 2;          // 0..1 (row half)
    const int wn   = wid & 3;           // 0..3 (col quarter)
    const int row0 = blockIdx.x * BM;

    const int l15 = lane & 15;
    const int l4  = lane >> 4;
    const int kge = l4 ^ ((l15 >> 1) & 3);          // swizzled kg for frag reads
    const int fragoff = l15 * 32 + kge * 8;         // halves within a 512-half subtile

    // x staging mapping: thread -> (row, 4-col chunk)
    const int sr = tid >> 2;            // 0..127
    const int sc = tid & 3;             // 0..3  (k: sc*4..sc*4+3 and +16)
    // C staging mapping: lane -> (col, pre-swizzled source kg)
    const int ccol = lane >> 2;                         // 0..15
    const int ckg  = (lane & 3) ^ ((ccol >> 1) & 3);    // inverse swizzle on source

    float best[4][4];
    int   bidx[4][4];
#pragma unroll
    for (int i = 0; i < 4; ++i)
#pragma unroll
        for (int r = 0; r < 4; ++r) { best[i][r] = 3.4e38f; bidx[i][r] = 0; }

    for (int kc = 0; kc < K_CENT; kc += BN) {
        floatx4 acc[4][4];
#pragma unroll
        for (int i = 0; i < 4; ++i)
#pragma unroll
            for (int j = 0; j < 4; ++j) acc[i][j] = (floatx4)0.0f;

        // ---- prologue: stage kd=0 into buf 0
        {
            _Float16* buf = lds[0];
            const float4 xv0 = *(const float4*)&x[(size_t)(row0 + sr) * D_DIM + 0 + sc * 4];
            const float4 xv1 = *(const float4*)&x[(size_t)(row0 + sr) * D_DIM + 16 + sc * 4];
            gload_lds16(&ChiT[(size_t)(kc + wid * 16       + ccol) * D_DIM + 0 + ckg * 8], buf + CHOFF + wid * 512);
            gload_lds16(&ChiT[(size_t)(kc + (wid + 8) * 16 + ccol) * D_DIM + 0 + ckg * 8], buf + CHOFF + (wid + 8) * 512);
            gload_lds16(&CloT[(size_t)(kc + wid * 16       + ccol) * D_DIM + 0 + ckg * 8], buf + CLOFF + wid * 512);
            gload_lds16(&CloT[(size_t)(kc + (wid + 8) * 16 + ccol) * D_DIM + 0 + ckg * 8], buf + CLOFF + (wid + 8) * 512);
            write_x(buf, xv0, sr, sc * 4);
            write_x(buf, xv1, sr, sc * 4 + 16);
            __syncthreads();
        }

        for (int kdi = 0; kdi < D_DIM / BK; ++kdi) {
            const int cur = kdi & 1;
            _Float16* bufc = lds[cur];
            _Float16* bufn = lds[cur ^ 1];
            const int  kdn = (kdi + 1) * BK;
            const bool pf  = (kdi + 1 < D_DIM / BK);

            float4 xv0, xv1;
            if (pf) {
                // issue next-stage loads early: x into regs, C direct to LDS
                xv0 = *(const float4*)&x[(size_t)(row0 + sr) * D_DIM + kdn + sc * 4];
                xv1 = *(const float4*)&x[(size_t)(row0 + sr) * D_DIM + kdn + 16 + sc * 4];
                gload_lds16(&ChiT[(size_t)(kc + wid * 16       + ccol) * D_DIM + kdn + ckg * 8], bufn + CHOFF + wid * 512);
                gload_lds16(&ChiT[(size_t)(kc + (wid + 8) * 16 + ccol) * D_DIM + kdn + ckg * 8], bufn + CHOFF + (wid + 8) * 512);
                gload_lds16(&CloT[(size_t)(kc + wid * 16       + ccol) * D_DIM + kdn + ckg * 8], bufn + CLOFF + wid * 512);
                gload_lds16(&CloT[(size_t)(kc + (wid + 8) * 16 + ccol) * D_DIM + kdn + ckg * 8], bufn + CLOFF + (wid + 8) * 512);
            }

            // fragment loads from current buffer
            half8 ah[4], al[4], bh[4], bl[4];
#pragma unroll
            for (int i = 0; i < 4; ++i) {
                ah[i] = *(const half8*)(bufc + XH + (wm * 4 + i) * 512 + fragoff);
                al[i] = *(const half8*)(bufc + XL + (wm * 4 + i) * 512 + fragoff);
            }
#pragma unroll
            for (int j = 0; j < 4; ++j) {
                bh[j] = *(const half8*)(bufc + CHOFF + (wn * 4 + j) * 512 + fragoff);
                bl[j] = *(const half8*)(bufc + CLOFF + (wn * 4 + j) * 512 + fragoff);
            }

#pragma unroll
            for (int i = 0; i < 4; ++i)
#pragma unroll
                for (int j = 0; j < 4; ++j) {
                    acc[i][j] = __builtin_amdgcn_mfma_f32_16x16x32_f16(ah[i], bh[j], acc[i][j], 0, 0, 0);
                    acc[i][j] = __builtin_amdgcn_mfma_f32_16x16x32_f16(ah[i], bl[j], acc[i][j], 0, 0, 0);
                    acc[i][j] = __builtin_amdgcn_mfma_f32_16x16x32_f16(al[i], bh[j], acc[i][j], 0, 0, 0);
                }

            if (pf) {
                write_x(bufn, xv0, sr, sc * 4);
                write_x(bufn, xv1, sr, sc * 4 + 16);
            }
            __syncthreads();
        }

        // ---- argmin epilogue for this 256-col chunk (wave covers cols kc+wn*64..+63)
        const int colw = kc + wn * 64;
#pragma unroll
        for (int ns = 0; ns < 4; ++ns) {
            const float cn = Cnorm[colw + ns * 16 + l15];
            const int   ix = colw + ns * 16 + l15;
#pragma unroll
            for (int i = 0; i < 4; ++i)
#pragma unroll
                for (int r = 0; r < 4; ++r) {
                    const float d = fmaf(-2.0f, acc[i][ns][r], cn);
                    if (d < best[i][r]) { best[i][r] = d; bidx[i][r] = ix; }
                }
        }
    }

    // ---- per-wave reduce over the 16 column-lanes -> LDS candidates
#pragma unroll
    for (int i = 0; i < 4; ++i)
#pragma unroll
        for (int r = 0; r < 4; ++r) {
            float d  = best[i][r];
            int   ix = bidx[i][r];
#pragma unroll
            for (int off = 1; off < 16; off <<= 1) {
                const float od = __shfl_xor(d, off, 64);
                const int   oi = __shfl_xor(ix, off, 64);
                if (od < d || (od == d && oi < ix)) { d = od; ix = oi; }
            }
            if (l15 == 0) {
                red_d[wm][i * 16 + l4 * 4 + r][wn] = d;
                red_i[wm][i * 16 + l4 * 4 + r][wn] = ix;
            }
        }
    __syncthreads();

    // ---- cross-wave (wn=0..3) final argmin, tie -> smaller index
    if (tid < BM) {
        const int h  = tid >> 6;
        const int rr = tid & 63;
        float bd = red_d[h][rr][0];
        int   bi = red_i[h][rr][0];
#pragma unroll
        for (int w = 1; w < 4; ++w) {
            const float od = red_d[h][rr][w];
            const int   oi = red_i[h][rr][w];
            if (od < bd || (od == bd && oi < bi)) { bd = od; bi = oi; }
        }
        out[row0 + tid] = bi;
    }
}

// ============================================================================
// Fallback (proven R1 fp32 kernel) — used only if ws is too small for C split
// ============================================================================
__global__ __launch_bounds__(256, 2) void kmeans_assign_f32(
    const float* __restrict__ x, const float* __restrict__ Cm,
    const float* __restrict__ Cnorm, int* __restrict__ out)
{
    __shared__ float xs[32][64];
    __shared__ float cs[32][64];
    const int tid = threadIdx.x;
    const int tx  = tid & 15;
    const int ty  = tid >> 4;
    const int row0 = blockIdx.x * 64;
    const int xr = tid >> 3, xc = tid & 7;
    const int cr = tid >> 4, cc = tid & 15;
    float best[4]; int bidx[4];
#pragma unroll
    for (int i = 0; i < 4; ++i) { best[i] = 3.4e38f; bidx[i] = 0; }
    for (int kc = 0; kc < K_CENT; kc += 64) {
        float acc[16];
#pragma unroll
        for (int i = 0; i < 16; ++i) acc[i] = 0.0f;
        for (int kd = 0; kd < D_DIM; kd += 32) {
            const float4 xv0 = *(const float4*)&x[(size_t)(row0 + xr) * D_DIM + kd + xc * 4];
            const float4 xv1 = *(const float4*)&x[(size_t)(row0 + xr + 32) * D_DIM + kd + xc * 4];
            const float4 cv0 = *(const float4*)&Cm[(size_t)(kd + cr) * K_CENT + kc + cc * 4];
            const float4 cv1 = *(const float4*)&Cm[(size_t)(kd + cr + 16) * K_CENT + kc + cc * 4];
            __syncthreads();
            xs[xc*4+0][xr] = xv0.x; xs[xc*4+1][xr] = xv0.y; xs[xc*4+2][xr] = xv0.z; xs[xc*4+3][xr] = xv0.w;
            xs[xc*4+0][xr+32] = xv1.x; xs[xc*4+1][xr+32] = xv1.y; xs[xc*4+2][xr+32] = xv1.z; xs[xc*4+3][xr+32] = xv1.w;
            *(float4*)&cs[cr][cc*4]    = cv0;
            *(float4*)&cs[cr+16][cc*4] = cv1;
            __syncthreads();
#pragma unroll
            for (int kk = 0; kk < 32; ++kk) {
                const float4 a = *(const float4*)&xs[kk][ty*4];
                const float4 b = *(const float4*)&cs[kk][tx*4];
                acc[ 0] += a.x*b.x; acc[ 1] += a.x*b.y; acc[ 2] += a.x*b.z; acc[ 3] += a.x*b.w;
                acc[ 4] += a.y*b.x; acc[ 5] += a.y*b.y; acc[ 6] += a.y*b.z; acc[ 7] += a.y*b.w;
                acc[ 8] += a.z*b.x; acc[ 9] += a.z*b.y; acc[10] += a.z*b.z; acc[11] += a.z*b.w;
                acc[12] += a.w*b.x; acc[13] += a.w*b.y; acc[14] += a.w*b.z; acc[15] += a.w*b.w;
            }
        }
        const float4 cn = *(const float4*)&Cnorm[kc + tx*4];
        const float cnv[4] = {cn.x, cn.y, cn.z, cn.w};
#pragma unroll
        for (int i = 0; i < 4; ++i)
#pragma unroll
            for (int j = 0; j < 4; ++j) {
                const float dist = cnv[j] - 2.0f * acc[i*4+j];
                const int   idx  = kc + tx*4 + j;
                if (dist < best[i]) { best[i] = dist; bidx[i] = idx; }
            }
    }
#pragma unroll
    for (int i = 0; i < 4; ++i) {
        float d = best[i]; int ix = bidx[i];
#pragma unroll
        for (int off = 1; off < 16; off <<= 1) {
            const float od = __shfl_xor(d, off, 64);
            const int   oi = __shfl_xor(ix, off, 64);
            if (od < d || (od == d && oi < ix)) { d = od; ix = oi; }
        }
        if (tx == 0) out[row0 + ty*4 + i] = ix;
    }
}

// ============================================================================
extern "C" void kernel_launch(void* const* d_in, const int* in_sizes, int n_in,
                              void* d_out, int out_size, void* d_ws, size_t ws_size,
                              hipStream_t stream) {
    const float* x     = (const float*)d_in[0];
    const float* C     = (const float*)d_in[1];
    const float* Cnorm = (const float*)d_in[2];
    int* out = (int*)d_out;

    const size_t chalf = (size_t)K_CENT * D_DIM;
    if (ws_size >= 2 * chalf * sizeof(_Float16)) {
        _Float16* ChiT = (_Float16*)d_ws;
        _Float16* CloT = ChiT + chalf;
        convert_C_kernel<<<dim3(128, 32), 256, 0, stream>>>(C, ChiT, CloT);
        kmeans_mfma_kernel<<<dim3(N_ROWS / BM), 512, 0, stream>>>(x, ChiT, CloT, Cnorm, out);
    } else {
        kmeans_assign_f32<<<dim3(N_ROWS / 64), 256, 0, stream>>>(x, C, Cnorm, out);
    }
}